// Round 7
// baseline (271.605 us; speedup 1.0000x reference)
//
#include <hip/hip_runtime.h>
#include <math.h>

#define NN 50        // neighbours
#define DD 128       // embedding dim
#define MT 4         // 4 m-tiles of 16 rows (50 padded to 64)
#define KT 4         // 4 k-tiles of 32 (K=128)
#define NIT 32       // b's per block  (grid = B/NIT = 1024)
#define TILE_B 25600 // 50*128*4 bytes per nbr tile
#define NPASS 25     // TILE_B / 1024

typedef __attribute__((ext_vector_type(4))) float  f32x4;
typedef __attribute__((ext_vector_type(2))) __fp16 f16x2;   // matches cvt_pkrtz return
typedef __attribute__((ext_vector_type(8))) __fp16 f16x8;

// fp32 scratch for W@A1 / W@A2, then fp16 transposed weight tables.
__device__ float g_WA1f[DD * DD];
__device__ float g_WA2f[DD * DD];
__device__ __attribute__((aligned(16))) __fp16 g_Wt[2 * DD * DD];  // [col 0..255][k]: [W | W@A2]^T
__device__ __attribute__((aligned(16))) __fp16 g_W1t[DD * DD];     // [col d][k]     : (W@A1)^T

__global__ void compute_WA(const float* __restrict__ W,
                           const float* __restrict__ A_w) {
    const int d = threadIdx.x, k = blockIdx.x, m = blockIdx.y;
    const float* __restrict__ A = A_w + (size_t)m * DD * DD;
    float acc = 0.f;
#pragma unroll 8
    for (int j = 0; j < DD; ++j)
        acc = fmaf(W[k * DD + j], A[j * DD + d], acc);
    if (m == 0) g_WA1f[k * DD + d] = acc;
    else        g_WA2f[k * DD + d] = acc;
}

__global__ void cvt_weights(const float* __restrict__ W) {
    const int n = blockIdx.x;      // 0..383
    const int k = threadIdx.x;     // 0..127
    if (n < DD)          g_Wt[n * DD + k]             = (__fp16)W[k * DD + n];
    else if (n < 2 * DD) g_Wt[n * DD + k]             = (__fp16)g_WA2f[k * DD + (n - DD)];
    else                 g_W1t[(n - 2 * DD) * DD + k] = (__fp16)g_WA1f[k * DD + (n - 2 * DD)];
}

// 8 consecutive fp32 -> 8 fp16 (packed RTZ converts, 4 instrs)
__device__ __forceinline__ f16x8 cvt8(float4 f0, float4 f1) {
    union { f16x2 h[4]; f16x8 v; } u;
    u.h[0] = __builtin_amdgcn_cvt_pkrtz(f0.x, f0.y);
    u.h[1] = __builtin_amdgcn_cvt_pkrtz(f0.z, f0.w);
    u.h[2] = __builtin_amdgcn_cvt_pkrtz(f1.x, f1.y);
    u.h[3] = __builtin_amdgcn_cvt_pkrtz(f1.z, f1.w);
    return u.v;
}

#define MFMA(a, b, c) __builtin_amdgcn_mfma_f32_16x16x32_f16((a), (b), (c), 0, 0, 0)

// 512 threads / 8 waves per block, 2 blocks/CU -> 4 waves/SIMD (r6 had only 2:
// every vmcnt/barrier stalled the SIMD; HBM queue went slack -> 52% of BW).
// Each wave owns 16 output cols (col = 16w + c) for both p=0 (pn) and p=1 (s):
// bF 32 + acc 32 + afr 16 regs -> fits the 128-VGPR cap of launch_bounds(512,4).
// Per-wave DMA count made uniform (4/tile) via dummy 4B loads so vmcnt(4) is exact.
__global__ __launch_bounds__(512, 4)
void attn_mfma(const float* __restrict__ x,
               const float* __restrict__ nbr,
               const float* __restrict__ A_b,
               float* __restrict__ out, int B) {
    __shared__ __attribute__((aligned(16))) char tiles[2][TILE_B];  // 51.2 KB
    __shared__ float pxa_lds[NIT][DD];                              // 16.4 KB
    __shared__ __attribute__((aligned(16))) char dummy_lds[256];    // dummy DMA sink

    const int tid  = threadIdx.x;
    const int w    = tid >> 6;     // 0..7
    const int lane = tid & 63;
    const int c    = lane & 15;    // A-row / B-col / D-col lane index
    const int g    = lane >> 4;    // k-group / D-row group
    const int bb   = blockIdx.x;
    const int grid = gridDim.x;

    // ---- Phase A: pxA for this block's NIT b's, cols 16w+c: x_rows @ W1t (+bias) ----
    {
        f32x4 pacc[NIT / 16];
#pragma unroll
        for (int mt = 0; mt < NIT / 16; ++mt) pacc[mt] = (f32x4)0.f;

#pragma unroll
        for (int mt = 0; mt < NIT / 16; ++mt) {
            long brow = (long)bb + (long)grid * (16 * mt + c);
            if (brow > B - 1) brow = B - 1;
            const float4* __restrict__ xp =
                reinterpret_cast<const float4*>(x + brow * DD);
#pragma unroll
            for (int kt = 0; kt < KT; ++kt) {
                const f16x8 a = cvt8(xp[8 * kt + 2 * g], xp[8 * kt + 2 * g + 1]);
                const f16x8 bw = *reinterpret_cast<const f16x8*>(
                    g_W1t + (16 * w + c) * DD + 32 * kt + 8 * g);
                pacc[mt] = MFMA(a, bw, pacc[mt]);
            }
        }
        const float ab = A_b[16 * w + c];
#pragma unroll
        for (int mt = 0; mt < NIT / 16; ++mt)
#pragma unroll
            for (int r = 0; r < 4; ++r)
                pxa_lds[16 * mt + 4 * g + r][16 * w + c] = pacc[mt][r] + ab;
    }

    // ---- main-GEMM B fragments, resident in VGPRs (pinned via opaque asm) ----
    f16x8 bF[2][KT];
#pragma unroll
    for (int p = 0; p < 2; ++p)
#pragma unroll
        for (int kt = 0; kt < KT; ++kt) {
            const int col = p * DD + 16 * w + c;
            bF[p][kt] = *reinterpret_cast<const f16x8*>(
                g_Wt + col * DD + 32 * kt + 8 * g);
            asm volatile("" : "+v"(bF[p][kt]));   // opaque: no remat/sink
        }

    __syncthreads();   // pxa_lds ready (full drain once, outside the loop)

    // Stage nbr tile `it` (or all-dummies if it<0) into LDS buffer `bufidx`.
    // LDS dest linear; XOR-swizzle (row&7)<<4 applied on the GLOBAL source.
    // Every wave issues exactly 4 VMEM ops per stage (dummies pad) -> vmcnt(4).
    auto stage = [&](int it, int bufidx) {
        const char* nb = (const char*)(nbr +
            (size_t)(bb + (size_t)grid * (it < 0 ? 0 : it)) * (NN * DD));
#pragma unroll
        for (int j = 0; j < 4; ++j) {
            const int p = w + 8 * j;            // wave w: passes w, w+8, w+16, w+24
            if (it >= 0 && p < NPASS) {
                const int dloc = p * 1024 + lane * 16;
                const int row  = dloc >> 9;     // 512 B per fp32 row
                const int src  = dloc ^ ((row & 7) << 4);
                __builtin_amdgcn_global_load_lds(
                    (const __attribute__((address_space(1))) void*)(nb + src),
                    (__attribute__((address_space(3))) void*)(&tiles[bufidx][p * 1024]),
                    16, 0, 0);
            } else {
                __builtin_amdgcn_global_load_lds(
                    (const __attribute__((address_space(1))) void*)x,
                    (__attribute__((address_space(3))) void*)dummy_lds, 4, 0, 0);
            }
        }
    };

    stage(0, 0);
    stage(1, 1);

    const float m0v = (g == 0) ? 1.f : 0.f;  // validity of rows 48,49 (mt=3,r<2)

#pragma unroll 1
    for (int i = 0; i < NIT; ++i) {
        // tile i arrived when only tile i+1's 4 DMA ops remain outstanding.
        asm volatile("s_waitcnt vmcnt(4)" ::: "memory");
        __builtin_amdgcn_s_barrier();

        const char* __restrict__ tile = tiles[i & 1];
        f32x4 acc[MT][2];
#pragma unroll
        for (int mt = 0; mt < MT; ++mt)
#pragma unroll
            for (int p = 0; p < 2; ++p) acc[mt][p] = (f32x4)0.f;

#pragma unroll
        for (int mt = 0; mt < MT; ++mt) {
            int row = 16 * mt + c;
            if (row > NN - 1) row = NN - 1;     // pad rows masked in softmax
            const int rb = row * 512;
            const int sw = (row & 7) << 4;
            f16x8 afr[KT];
#pragma unroll
            for (int kt = 0; kt < KT; ++kt) {
                const int off = rb + kt * 128 + g * 32;
                const float4 lo = *(const float4*)(tile + ((off) ^ sw));
                const float4 hi = *(const float4*)(tile + ((off + 16) ^ sw));
                afr[kt] = cvt8(lo, hi);
            }
#pragma unroll
            for (int kt = 0; kt < KT; ++kt)
#pragma unroll
                for (int p = 0; p < 2; ++p)
                    acc[mt][p] = MFMA(afr[kt], bF[p][kt], acc[mt][p]);
        }

        // softmax over n for this wave's col (no max-shift: logits ~N(0,1.4))
        {
            const float pxa = pxa_lds[i][16 * w + c];
            float den = 0.f, num = 0.f;
#pragma unroll
            for (int mt = 0; mt < MT; ++mt)
#pragma unroll
                for (int r = 0; r < 4; ++r) {
                    if (mt == 3 && r >= 2) continue;     // n >= 52: never valid
                    float t = pxa + acc[mt][1][r];
                    t = fmaxf(t, 0.2f * t);              // leaky_relu(0.2)
                    float p = __expf(t);
                    if (mt == 3) p *= m0v;               // n=48,49 valid iff g==0
                    den += p;
                    num = fmaf(p, acc[mt][0][r], num);
                }
            den += __shfl_xor(den, 16); den += __shfl_xor(den, 32);
            num += __shfl_xor(num, 16); num += __shfl_xor(num, 32);
            if (g == 0) out[(size_t)(bb + (size_t)grid * i) * DD + 16 * w + c] =
                __fdividef(num, den);
        }

        // all LDS reads of this tile done before other waves may overwrite it
        asm volatile("s_waitcnt lgkmcnt(0)" ::: "memory");
        __builtin_amdgcn_sched_barrier(0);
        __builtin_amdgcn_s_barrier();

        const int t2 = i + 2;
        stage(t2 < NIT ? t2 : -1, i & 1);   // tail: dummies keep vmcnt uniform
    }
}

extern "C" void kernel_launch(void* const* d_in, const int* in_sizes, int n_in,
                              void* d_out, int out_size, void* d_ws, size_t ws_size,
                              hipStream_t stream) {
    const float* x   = (const float*)d_in[0];  // [B, D]
    const float* nbr = (const float*)d_in[1];  // [B, N, D]
    const float* W   = (const float*)d_in[2];  // [D, D]
    const float* A_w = (const float*)d_in[3];  // [2D, D]
    const float* A_b = (const float*)d_in[4];  // [D]
    float* out = (float*)d_out;                // [B, D]
    const int B = in_sizes[0] / DD;

    compute_WA<<<dim3(DD, 2), DD, 0, stream>>>(W, A_w);
    cvt_weights<<<3 * DD, DD, 0, stream>>>(W);
    const int grid = (B + NIT - 1) / NIT;      // 1024 blocks
    attn_mfma<<<grid, 512, 0, stream>>>(x, nbr, A_b, out, B);
}

// Round 8
// 252.615 us; speedup vs baseline: 1.0752x; 1.0752x over previous
//
#include <hip/hip_runtime.h>
#include <math.h>

#define NN 50          // neighbours
#define DD 128         // embedding dim
#define MT 4           // 4 m-tiles of 16 rows (50 rows + x-row padded to 64)
#define KT 4           // 4 k-tiles of 32 (K=128)
#define NIT 64         // b's per block  (grid = B/NIT = 512 = exactly 2 blocks/CU)
#define ROWS 51        // 50 nbr rows + 1 x row
#define TILE_B (ROWS * 512)   // 26112 B per fp32 tile
#define NBUF 3

typedef __attribute__((ext_vector_type(4))) float  f32x4;
typedef __attribute__((ext_vector_type(2))) __fp16 f16x2;   // matches cvt_pkrtz return
typedef __attribute__((ext_vector_type(8))) __fp16 f16x8;

// fp32 scratch for W@A1 / W@A2, then one fused fp16 transposed weight table.
__device__ float g_WA1f[DD * DD];
__device__ float g_WA2f[DD * DD];
__device__ __attribute__((aligned(16))) __fp16 g_Wt[3 * DD * DD]; // [col 0..383][k]: [W | W@A2 | W@A1]^T

__global__ void compute_WA(const float* __restrict__ W,
                           const float* __restrict__ A_w) {
    const int d = threadIdx.x, k = blockIdx.x, m = blockIdx.y;
    const float* __restrict__ A = A_w + (size_t)m * DD * DD;
    float acc = 0.f;
#pragma unroll 8
    for (int j = 0; j < DD; ++j)
        acc = fmaf(W[k * DD + j], A[j * DD + d], acc);
    if (m == 0) g_WA1f[k * DD + d] = acc;
    else        g_WA2f[k * DD + d] = acc;
}

__global__ void cvt_weights(const float* __restrict__ W) {
    const int n = blockIdx.x;      // 0..383
    const int k = threadIdx.x;     // 0..127
    float v;
    if (n < DD)          v = W[k * DD + n];
    else if (n < 2 * DD) v = g_WA2f[k * DD + (n - DD)];
    else                 v = g_WA1f[k * DD + (n - 2 * DD)];
    g_Wt[n * DD + k] = (__fp16)v;
}

// 8 consecutive fp32 -> 8 fp16 (packed RTZ converts, 4 instrs)
__device__ __forceinline__ f16x8 cvt8(float4 f0, float4 f1) {
    union { f16x2 h[4]; f16x8 v; } u;
    u.h[0] = __builtin_amdgcn_cvt_pkrtz(f0.x, f0.y);
    u.h[1] = __builtin_amdgcn_cvt_pkrtz(f0.z, f0.w);
    u.h[2] = __builtin_amdgcn_cvt_pkrtz(f1.x, f1.y);
    u.h[3] = __builtin_amdgcn_cvt_pkrtz(f1.z, f1.w);
    return u.v;
}

#define MFMA(a, b, c) __builtin_amdgcn_mfma_f32_16x16x32_f16((a), (b), (c), 0, 0, 0)

// 256 threads / 4 waves, 2 blocks/CU. A-tile = [nbr(50); x(1)] so the pxa GEMM
// rides inside the main MFMA (extract row 50 of the WA1-part from the acc).
// 3-deep tile pipeline staged by global_load_lds DMA. vmcnt discipline with
// EXACT accounting: per iter each wave issues 7 DMA + 2 out-stores; r6/r7's
// vmcnt(6)/(4) forgot the stores and synchronously drained ~half of tile i+2's
// transfer every iteration (the measured 2x-over-floor period).
__global__ __launch_bounds__(256, 2)
void attn_mfma(const float* __restrict__ x,
               const float* __restrict__ nbr,
               const float* __restrict__ A_b,
               float* __restrict__ out, int B) {
    __shared__ __attribute__((aligned(16))) char tiles[NBUF][TILE_B]; // 76.5 KB
    __shared__ __attribute__((aligned(16))) char dummy_lds[64];

    const int tid  = threadIdx.x;
    const int w    = tid >> 6;     // 0..3
    const int lane = tid & 63;
    const int c    = lane & 15;    // A-row / B-col / D-col lane index
    const int g    = lane >> 4;    // k-group / D-row group
    const size_t b0 = (size_t)blockIdx.x * NIT;

    // ---- B fragments for all 3 parts, resident in VGPRs (pinned) ----
    f16x8 bF[3][2][KT];            // 96 VGPRs
#pragma unroll
    for (int p = 0; p < 3; ++p)
#pragma unroll
        for (int nt = 0; nt < 2; ++nt)
#pragma unroll
            for (int kt = 0; kt < KT; ++kt) {
                const int col = p * DD + 32 * w + 16 * nt + c;
                bF[p][nt][kt] = *reinterpret_cast<const f16x8*>(
                    g_Wt + col * DD + 32 * kt + 8 * g);
                asm volatile("" : "+v"(bF[p][nt][kt]));   // no remat/sink
            }
    float ab0 = A_b[32 * w + c];
    float ab1 = A_b[32 * w + 16 + c];
    asm volatile("" : "+v"(ab0), "+v"(ab1));  // materialize + drain before staging

    // Stage tile `it` (or all-dummies if it<0) into LDS at dst.
    // LDS dest linear (wave-uniform base + lane*16); XOR-swizzle (row&7)<<4
    // pre-applied on the GLOBAL source. Exactly 7 DMA ops per wave per stage.
    auto stage = [&](int it, char* dst) {
        const size_t bidx = b0 + (size_t)(it < 0 ? 0 : it);
        const char* nb = (const char*)(nbr + bidx * (NN * DD));
        const char* xb = (const char*)(x + bidx * DD);
#pragma unroll
        for (int j = 0; j < 7; ++j) {
            const int p = w + 4 * j;            // 0..27
            if (it >= 0 && p < 25) {            // nbr rows: 25 KB in 25 passes
                const int dloc = p * 1024 + lane * 16;
                const int row  = dloc >> 9;     // 512 B per fp32 row
                const int src  = dloc ^ ((row & 7) << 4);
                __builtin_amdgcn_global_load_lds(
                    (const __attribute__((address_space(1))) void*)(nb + src),
                    (__attribute__((address_space(3))) void*)(dst + p * 1024),
                    16, 0, 0);
            } else if (it >= 0 && p == 25) {    // x row -> tile row 50 (512 B)
                if (lane < 32) {
                    const int src = (lane * 16) ^ ((50 & 7) << 4);
                    __builtin_amdgcn_global_load_lds(
                        (const __attribute__((address_space(1))) void*)(xb + src),
                        (__attribute__((address_space(3))) void*)(dst + 50 * 512),
                        16, 0, 0);
                }
            } else {                            // pad: uniform per-wave op count
                __builtin_amdgcn_global_load_lds(
                    (const __attribute__((address_space(1))) void*)x,
                    (__attribute__((address_space(3))) void*)dummy_lds, 4, 0, 0);
            }
        }
    };

    char* bufA = tiles[0];   // tile i   (compute)
    char* bufB = tiles[1];   // tile i+1 (in flight)
    char* bufC = tiles[2];   // tile i+2 (stage target)

    stage(0, bufA);
    stage(1, bufB);
#pragma unroll
    for (int j = 0; j < 4; ++j)   // prologue pad -> vmcnt(18) exact at iter 0
        __builtin_amdgcn_global_load_lds(
            (const __attribute__((address_space(1))) void*)x,
            (__attribute__((address_space(3))) void*)dummy_lds, 4, 0, 0);

    const float m0v = (g == 0) ? 1.f : 0.f;  // rows 48,49 valid iff g==0 (mt=3,r<2)

#pragma unroll 1
    for (int i = 0; i < NIT; ++i) {
        const int t2 = i + 2;
        stage(t2 < NIT ? t2 : -1, bufC);

        // Ops newer than tile i's last DMA: stores(i-2)=2 + stage(i+1)=7 +
        // stores(i-1)=2 + stage(i+2)=7 -> wait vmcnt(18) = tile i exactly done.
        asm volatile("s_waitcnt vmcnt(18)" ::: "memory");
        __builtin_amdgcn_s_barrier();   // all waves' slices of tile i arrived

        const char* __restrict__ tile = bufA;
        f32x4 acc[MT][2][2];
        f32x4 acc2[2];
#pragma unroll
        for (int mt = 0; mt < MT; ++mt)
#pragma unroll
            for (int p = 0; p < 2; ++p)
#pragma unroll
                for (int nt = 0; nt < 2; ++nt) acc[mt][p][nt] = (f32x4)0.f;
        acc2[0] = (f32x4)0.f; acc2[1] = (f32x4)0.f;

#pragma unroll
        for (int mt = 0; mt < MT; ++mt) {
            int row = 16 * mt + c;
            if (row > 50) row = 50;             // mt=3: rows 51..63 -> x-row, masked
            const int rb = row * 512;
            const int sw = (row & 7) << 4;
            f16x8 afr[KT];
#pragma unroll
            for (int kt = 0; kt < KT; ++kt) {
                const int off = rb + kt * 128 + g * 32;
                const float4 lo = *(const float4*)(tile + ((off) ^ sw));
                const float4 hi = *(const float4*)(tile + ((off + 16) ^ sw));
                afr[kt] = cvt8(lo, hi);
            }
#pragma unroll
            for (int kt = 0; kt < KT; ++kt)
#pragma unroll
                for (int p = 0; p < 2; ++p)
#pragma unroll
                    for (int nt = 0; nt < 2; ++nt)
                        acc[mt][p][nt] = MFMA(afr[kt], bF[p][nt][kt], acc[mt][p][nt]);
            if (mt == 3) {                      // pxa part: only row 50 needed
#pragma unroll
                for (int kt = 0; kt < KT; ++kt)
#pragma unroll
                    for (int nt = 0; nt < 2; ++nt)
                        acc2[nt] = MFMA(afr[kt], bF[2][nt][kt], acc2[nt]);
            }
        }

        // softmax over n per col (no max-shift: logits ~N(0,1.4), exp safe)
#pragma unroll
        for (int nt = 0; nt < 2; ++nt) {
            // row 50 (= 48 + 4*0 + 2) of the WA1 part: lanes g==0, reg r=2
            const float pxa = __shfl(acc2[nt][2], c) + (nt ? ab1 : ab0);
            float den = 0.f, num = 0.f;
#pragma unroll
            for (int mt = 0; mt < MT; ++mt)
#pragma unroll
                for (int r = 0; r < 4; ++r) {
                    if (mt == 3 && r >= 2) continue;     // n >= 52: never valid
                    float t = pxa + acc[mt][1][nt][r];
                    t = fmaxf(t, 0.2f * t);              // leaky_relu(0.2)
                    float p = __expf(t);
                    if (mt == 3) p *= m0v;               // n=48,49 valid iff g==0
                    den += p;
                    num = fmaf(p, acc[mt][0][nt][r], num);
                }
            den += __shfl_xor(den, 16); den += __shfl_xor(den, 32);
            num += __shfl_xor(num, 16); num += __shfl_xor(num, 32);
            if (g == 0) out[(b0 + i) * DD + 32 * w + 16 * nt + c] =
                __fdividef(num, den);
        }

        // all LDS reads of tile i done before any wave re-stages this buffer
        asm volatile("s_waitcnt lgkmcnt(0)" ::: "memory");
        __builtin_amdgcn_sched_barrier(0);
        __builtin_amdgcn_s_barrier();

        char* t0 = bufA; bufA = bufB; bufB = bufC; bufC = t0;
    }
}

extern "C" void kernel_launch(void* const* d_in, const int* in_sizes, int n_in,
                              void* d_out, int out_size, void* d_ws, size_t ws_size,
                              hipStream_t stream) {
    const float* x   = (const float*)d_in[0];  // [B, D]
    const float* nbr = (const float*)d_in[1];  // [B, N, D]
    const float* W   = (const float*)d_in[2];  // [D, D]
    const float* A_w = (const float*)d_in[3];  // [2D, D]
    const float* A_b = (const float*)d_in[4];  // [D]
    float* out = (float*)d_out;                // [B, D]
    const int B = in_sizes[0] / DD;

    compute_WA<<<dim3(DD, 2), DD, 0, stream>>>(W, A_w);
    cvt_weights<<<3 * DD, DD, 0, stream>>>(W);
    const int grid = (B + NIT - 1) / NIT;      // 512 blocks = 2/CU, one round
    attn_mfma<<<grid, 256, 0, stream>>>(x, nbr, A_b, out, B);
}

// Round 9
// 219.163 us; speedup vs baseline: 1.2393x; 1.1526x over previous
//
#include <hip/hip_runtime.h>
#include <math.h>

#define NN 50          // neighbours
#define DD 128         // embedding dim
#define MT 4           // 4 m-tiles of 16 rows (50 rows + x-row padded to 64)
#define KT 4           // 4 k-tiles of 32 (K=128)
#define NIT 64         // b's per block  (grid = B/NIT = 512 = 2 blocks/CU)
#define TILE_H 13056   // 51 rows * 256 B (fp16 tile)

typedef __attribute__((ext_vector_type(4))) float  f32x4;
typedef __attribute__((ext_vector_type(2))) __fp16 f16x2;   // cvt_pkrtz return type
typedef __attribute__((ext_vector_type(4))) __fp16 f16x4;
typedef __attribute__((ext_vector_type(8))) __fp16 f16x8;

// fp32 scratch for W@A1 / W@A2, then one fused fp16 transposed weight table.
__device__ float g_WA1f[DD * DD];
__device__ float g_WA2f[DD * DD];
__device__ __attribute__((aligned(16))) __fp16 g_Wt[3 * DD * DD]; // [col 0..383][k]: [W | W@A2 | W@A1]^T

__global__ void compute_WA(const float* __restrict__ W,
                           const float* __restrict__ A_w) {
    const int d = threadIdx.x, k = blockIdx.x, m = blockIdx.y;
    const float* __restrict__ A = A_w + (size_t)m * DD * DD;
    float acc = 0.f;
#pragma unroll 8
    for (int j = 0; j < DD; ++j)
        acc = fmaf(W[k * DD + j], A[j * DD + d], acc);
    if (m == 0) g_WA1f[k * DD + d] = acc;
    else        g_WA2f[k * DD + d] = acc;
}

__global__ void cvt_weights(const float* __restrict__ W) {
    const int n = blockIdx.x;      // 0..383
    const int k = threadIdx.x;     // 0..127
    float v;
    if (n < DD)          v = W[k * DD + n];
    else if (n < 2 * DD) v = g_WA2f[k * DD + (n - DD)];
    else                 v = g_WA1f[k * DD + (n - 2 * DD)];
    g_Wt[n * DD + k] = (__fp16)v;
}

#define MFMA(a, b, c) __builtin_amdgcn_mfma_f32_16x16x32_f16((a), (b), (c), 0, 0, 0)

// Reg-staged pipeline (r6-r8's global_load_lds with XOR-swizzled global source
// stuck at ~2x the HBM floor across 3 different schedules -> the DMA transfer
// path itself was the wall). Here: plain global_load_dwordx4 with ASCENDING
// addresses -> VGPRs; fp32->fp16 convert once at staging; ds_write_b64 at
// XOR-swizzled LDS addr (write+read same XOR; 2-way max = free). Register
// dependencies make the compiler's own counted vmcnt exact - no manual vmcnt.
// A-tile = [nbr(50); x(1)] so pxa rides in the main MFMA (row 50 of WA1 part).
__global__ __launch_bounds__(256, 2)
void attn_mfma(const float* __restrict__ x,
               const float* __restrict__ nbr,
               const float* __restrict__ A_b,
               float* __restrict__ out, int B) {
    __shared__ __attribute__((aligned(16))) char tiles[2][TILE_H];  // 26.1 KB

    const int tid  = threadIdx.x;
    const int w    = tid >> 6;     // 0..3
    const int lane = tid & 63;
    const int c    = lane & 15;    // A-row / B-col / D-col lane index
    const int g    = lane >> 4;    // k-group / D-row group
    const size_t b0 = (size_t)blockIdx.x * NIT;

    // ---- B fragments for all 3 parts, resident in VGPRs (pinned) ----
    f16x8 bF[3][2][KT];            // 96 VGPRs
#pragma unroll
    for (int p = 0; p < 3; ++p)
#pragma unroll
        for (int nt = 0; nt < 2; ++nt)
#pragma unroll
            for (int kt = 0; kt < KT; ++kt) {
                const int col = p * DD + 32 * w + 16 * nt + c;
                bF[p][nt][kt] = *reinterpret_cast<const f16x8*>(
                    g_Wt + col * DD + 32 * kt + 8 * g);
                asm volatile("" : "+v"(bF[p][nt][kt]));   // no remat/sink
            }
    float ab0 = A_b[32 * w + c];
    float ab1 = A_b[32 * w + 16 + c];
    asm volatile("" : "+v"(ab0), "+v"(ab1));

    // ---- staging registers: one tile (wave's 7 chunks) + x row ----
    float4 ra[7];                  // 28 VGPRs
    float2 rx;

    // Issue global loads for tile `it` (clean ascending addresses).
    auto load_tile = [&](int it) {
        int itc = it < NIT ? it : NIT - 1;        // tail: harmless re-load
        size_t bidx = b0 + (size_t)itc;
        if (bidx > (size_t)(B - 1)) bidx = (size_t)(B - 1);
        const float4* __restrict__ nb4 =
            reinterpret_cast<const float4*>(nbr + bidx * (size_t)(NN * DD));
#pragma unroll
        for (int j = 0; j < 7; ++j) {
            const int p = w + 4 * j;              // wave-uniform pass id, 0..27
            if (p < 25) ra[j] = nb4[p * 64 + lane];
        }
        if (w == 1)
            rx = reinterpret_cast<const float2*>(x + bidx * DD)[lane];
    };

    // Convert + write staged tile into LDS. fp16 row = 256 B; byte addr
    // XOR-swizzled by ((row&7)<<4) — identical XOR on the read side.
    auto write_tile = [&](char* dst) {
#pragma unroll
        for (int j = 0; j < 7; ++j) {
            const int p = w + 4 * j;
            if (p < 25) {
                const int lb  = p * 512 + lane * 8;   // fp16-tile byte offset
                const int row = lb >> 8;
                const int ad  = lb ^ ((row & 7) << 4);
                union { f16x2 h[2]; f16x4 v; } u;
                u.h[0] = __builtin_amdgcn_cvt_pkrtz(ra[j].x, ra[j].y);
                u.h[1] = __builtin_amdgcn_cvt_pkrtz(ra[j].z, ra[j].w);
                *reinterpret_cast<f16x4*>(dst + ad) = u.v;   // ds_write_b64
            }
        }
        if (w == 1) {   // x row -> tile row 50
            const int lb = 50 * 256 + lane * 4;
            const int ad = lb ^ ((50 & 7) << 4);
            *reinterpret_cast<f16x2*>(dst + ad) =
                __builtin_amdgcn_cvt_pkrtz(rx.x, rx.y);
        }
    };

    // ---- prologue: tile0 -> LDS, tile1 -> regs ----
    load_tile(0);
    write_tile(tiles[0]);          // compiler inserts exact vmcnt for ra
    load_tile(1);
    asm volatile("s_waitcnt lgkmcnt(0)" ::: "memory");
    __builtin_amdgcn_sched_barrier(0);
    __builtin_amdgcn_s_barrier();  // tiles[0] visible to all waves

    const float m0v = (g == 0) ? 1.f : 0.f;  // rows 48,49 valid iff g==0 (mt=3,r<2)

#pragma unroll 1
    for (int i = 0; i < NIT; ++i) {
        // (a) regs (tile i+1) -> LDS buf[(i+1)&1]  (compiler-counted vmcnt)
        write_tile(tiles[(i + 1) & 1]);
        // (b) issue loads for tile i+2 (HBM latency hides under (c))
        load_tile(i + 2);
        __builtin_amdgcn_sched_barrier(0);   // pin load-issue ABOVE compute

        // (c) compute tile i
        const char* __restrict__ tile = tiles[i & 1];
        f32x4 acc[MT][2][2];
        f32x4 acc2[2];
#pragma unroll
        for (int mt = 0; mt < MT; ++mt)
#pragma unroll
            for (int p = 0; p < 2; ++p)
#pragma unroll
                for (int nt = 0; nt < 2; ++nt) acc[mt][p][nt] = (f32x4)0.f;
        acc2[0] = (f32x4)0.f; acc2[1] = (f32x4)0.f;

#pragma unroll
        for (int mt = 0; mt < MT; ++mt) {
            int row = 16 * mt + c;
            if (row > 50) row = 50;          // mt=3: rows 51..63 -> x-row, masked
            const int rb = row * 256;
            const int sw = (row & 7) << 4;
            f16x8 afr[KT];
#pragma unroll
            for (int kt = 0; kt < KT; ++kt)
                afr[kt] = *reinterpret_cast<const f16x8*>(
                    tile + ((rb + kt * 64 + g * 16) ^ sw));
#pragma unroll
            for (int kt = 0; kt < KT; ++kt)
#pragma unroll
                for (int p = 0; p < 2; ++p)
#pragma unroll
                    for (int nt = 0; nt < 2; ++nt)
                        acc[mt][p][nt] = MFMA(afr[kt], bF[p][nt][kt], acc[mt][p][nt]);
            if (mt == 3) {                   // pxa part: only row 50 needed
#pragma unroll
                for (int kt = 0; kt < KT; ++kt)
#pragma unroll
                    for (int nt = 0; nt < 2; ++nt)
                        acc2[nt] = MFMA(afr[kt], bF[2][nt][kt], acc2[nt]);
            }
        }

        // softmax over n per col (no max-shift: logits ~N(0,1.4), exp safe)
#pragma unroll
        for (int nt = 0; nt < 2; ++nt) {
            // tile row 50 = local row 2 of mt=3 -> lanes g==0, reg r=2
            const float pxa = __shfl(acc2[nt][2], c) + (nt ? ab1 : ab0);
            float den = 0.f, num = 0.f;
#pragma unroll
            for (int mt = 0; mt < MT; ++mt)
#pragma unroll
                for (int r = 0; r < 4; ++r) {
                    if (mt == 3 && r >= 2) continue;     // n >= 52: never valid
                    float t = pxa + acc[mt][1][nt][r];
                    t = fmaxf(t, 0.2f * t);              // leaky_relu(0.2)
                    float p = __expf(t);
                    if (mt == 3) p *= m0v;               // n=48,49 valid iff g==0
                    den += p;
                    num = fmaf(p, acc[mt][0][nt][r], num);
                }
            den += __shfl_xor(den, 16); den += __shfl_xor(den, 32);
            num += __shfl_xor(num, 16); num += __shfl_xor(num, 32);
            if (g == 0) out[(b0 + i) * DD + 32 * w + 16 * nt + c] =
                __fdividef(num, den);
        }

        // (d) all LDS ops done before any wave rewrites buffers next iter
        asm volatile("s_waitcnt lgkmcnt(0)" ::: "memory");
        __builtin_amdgcn_sched_barrier(0);
        __builtin_amdgcn_s_barrier();
    }
}

extern "C" void kernel_launch(void* const* d_in, const int* in_sizes, int n_in,
                              void* d_out, int out_size, void* d_ws, size_t ws_size,
                              hipStream_t stream) {
    const float* x   = (const float*)d_in[0];  // [B, D]
    const float* nbr = (const float*)d_in[1];  // [B, N, D]
    const float* W   = (const float*)d_in[2];  // [D, D]
    const float* A_w = (const float*)d_in[3];  // [2D, D]
    const float* A_b = (const float*)d_in[4];  // [D]
    float* out = (float*)d_out;                // [B, D]
    const int B = in_sizes[0] / DD;

    compute_WA<<<dim3(DD, 2), DD, 0, stream>>>(W, A_w);
    cvt_weights<<<3 * DD, DD, 0, stream>>>(W);
    const int grid = (B + NIT - 1) / NIT;      // 512 blocks = 2/CU, one round
    attn_mfma<<<grid, 256, 0, stream>>>(x, nbr, A_b, out, B);
}

// Round 10
// 214.856 us; speedup vs baseline: 1.2641x; 1.0200x over previous
//
#include <hip/hip_runtime.h>
#include <math.h>

#define NN 50          // neighbours
#define DD 128         // embedding dim
#define MT 4           // 4 m-tiles of 16 rows (50 padded to 64)
#define KT 4           // 4 k-tiles of 32 (K=128)
#define NIT 64         // b's per block  (grid = B/NIT = 512 = 2 blocks/CU)
#define TILE_H 12800   // 50 rows * 256 B (fp16 tile)

typedef __attribute__((ext_vector_type(4))) float  f32x4;
typedef __attribute__((ext_vector_type(2))) __fp16 f16x2;   // cvt_pkrtz return type
typedef __attribute__((ext_vector_type(4))) __fp16 f16x4;
typedef __attribute__((ext_vector_type(8))) __fp16 f16x8;

// fp32 scratch for W@A1 / W@A2, then fp16 transposed weight tables.
__device__ float g_WA1f[DD * DD];
__device__ float g_WA2f[DD * DD];
__device__ __attribute__((aligned(16))) __fp16 g_Wt[2 * DD * DD];  // [col 0..255][k]: [W | W@A2]^T
__device__ __attribute__((aligned(16))) __fp16 g_W1t[DD * DD];     // [col d][k]     : (W@A1)^T

__global__ void compute_WA(const float* __restrict__ W,
                           const float* __restrict__ A_w) {
    const int d = threadIdx.x, k = blockIdx.x, m = blockIdx.y;
    const float* __restrict__ A = A_w + (size_t)m * DD * DD;
    float acc = 0.f;
#pragma unroll 8
    for (int j = 0; j < DD; ++j)
        acc = fmaf(W[k * DD + j], A[j * DD + d], acc);
    if (m == 0) g_WA1f[k * DD + d] = acc;
    else        g_WA2f[k * DD + d] = acc;
}

__global__ void cvt_weights(const float* __restrict__ W) {
    const int n = blockIdx.x;      // 0..383
    const int k = threadIdx.x;     // 0..127
    if (n < DD)          g_Wt[n * DD + k]             = (__fp16)W[k * DD + n];
    else if (n < 2 * DD) g_Wt[n * DD + k]             = (__fp16)g_WA2f[k * DD + (n - DD)];
    else                 g_W1t[(n - 2 * DD) * DD + k] = (__fp16)g_WA1f[k * DD + (n - 2 * DD)];
}

// 8 consecutive fp32 -> 8 fp16 (packed RTZ converts, 4 instrs)
__device__ __forceinline__ f16x8 cvt8(float4 f0, float4 f1) {
    union { f16x2 h[4]; f16x8 v; } u;
    u.h[0] = __builtin_amdgcn_cvt_pkrtz(f0.x, f0.y);
    u.h[1] = __builtin_amdgcn_cvt_pkrtz(f0.z, f0.w);
    u.h[2] = __builtin_amdgcn_cvt_pkrtz(f1.x, f1.y);
    u.h[3] = __builtin_amdgcn_cvt_pkrtz(f1.z, f1.w);
    return u.v;
}

#define MFMA(a, b, c) __builtin_amdgcn_mfma_f32_16x16x32_f16((a), (b), (c), 0, 0, 0)

// v10: same reg-staged pipeline as r9 (the proven transfer path) but 512
// threads / 8 waves, each wave owning 16 output cols -> per-wave state
// ~120 VGPR, launch_bounds(512,4) => 4 waves/SIMD (r9: 2). r9's 8220 cy/iter
// vs ~5000 cy of max(component) was barrier/wait serialization at low
// occupancy. pxa precomputed in Phase A (frees the bF[2]/acc2 regs).
__global__ __launch_bounds__(512, 4)
void attn_mfma(const float* __restrict__ x,
               const float* __restrict__ nbr,
               const float* __restrict__ A_b,
               float* __restrict__ out, int B) {
    __shared__ __attribute__((aligned(16))) char tiles[2][TILE_H];  // 25.6 KB
    __shared__ float pxa_lds[NIT][DD];                              // 32.8 KB

    const int tid  = threadIdx.x;
    const int w    = tid >> 6;     // 0..7
    const int lane = tid & 63;
    const int c    = lane & 15;    // A-row / B-col / D-col lane index
    const int g    = lane >> 4;    // k-group / D-row group
    const size_t b0 = (size_t)blockIdx.x * NIT;
    const int col  = 16 * w + c;   // this wave's output column

    // ---- Phase A: pxa_lds[i][col] = A_b[col] + (x[b0+i] @ WA1)[col] ----
    {
        f32x4 pacc[MT];
#pragma unroll
        for (int mt = 0; mt < MT; ++mt) pacc[mt] = (f32x4)0.f;
#pragma unroll
        for (int mt = 0; mt < MT; ++mt) {
            long brow = (long)b0 + 16 * mt + c;
            if (brow > B - 1) brow = B - 1;
            const float4* __restrict__ xp =
                reinterpret_cast<const float4*>(x + brow * DD);
#pragma unroll
            for (int kt = 0; kt < KT; ++kt) {
                const f16x8 a = cvt8(xp[8 * kt + 2 * g], xp[8 * kt + 2 * g + 1]);
                const f16x8 bw = *reinterpret_cast<const f16x8*>(
                    g_W1t + col * DD + 32 * kt + 8 * g);
                pacc[mt] = MFMA(a, bw, pacc[mt]);
            }
        }
        const float ab = A_b[col];
#pragma unroll
        for (int mt = 0; mt < MT; ++mt)
#pragma unroll
            for (int r = 0; r < 4; ++r)
                pxa_lds[16 * mt + 4 * g + r][col] = pacc[mt][r] + ab;
    }

    // ---- B fragments (this wave's 16 cols, parts W and WA2), pinned ----
    f16x8 bF[2][KT];               // 32 VGPRs
#pragma unroll
    for (int p = 0; p < 2; ++p)
#pragma unroll
        for (int kt = 0; kt < KT; ++kt) {
            bF[p][kt] = *reinterpret_cast<const f16x8*>(
                g_Wt + (p * DD + col) * DD + 32 * kt + 8 * g);
            asm volatile("" : "+v"(bF[p][kt]));   // no remat/sink
        }

    // ---- staging registers: wave's share of one tile (<=4 chunks) ----
    float4 ra[4];                  // 16 VGPRs

    auto load_tile = [&](int it) {
        int itc = it < NIT ? it : NIT - 1;        // tail: harmless re-load
        size_t bidx = b0 + (size_t)itc;
        if (bidx > (size_t)(B - 1)) bidx = (size_t)(B - 1);
        const float4* __restrict__ nb4 =
            reinterpret_cast<const float4*>(nbr + bidx * (size_t)(NN * DD));
#pragma unroll
        for (int j = 0; j < 4; ++j) {
            const int p = w + 8 * j;              // wave-uniform pass id
            if (p < 25) ra[j] = nb4[p * 64 + lane];
        }
    };

    // fp16 tile row = 256 B; byte addr XOR-swizzled by ((row&7)<<4).
    auto write_tile = [&](char* dst) {
#pragma unroll
        for (int j = 0; j < 4; ++j) {
            const int p = w + 8 * j;
            if (p < 25) {
                const int lb  = p * 512 + lane * 8;   // fp16-tile byte offset
                const int row = lb >> 8;
                const int ad  = lb ^ ((row & 7) << 4);
                union { f16x2 h[2]; f16x4 v; } u;
                u.h[0] = __builtin_amdgcn_cvt_pkrtz(ra[j].x, ra[j].y);
                u.h[1] = __builtin_amdgcn_cvt_pkrtz(ra[j].z, ra[j].w);
                *reinterpret_cast<f16x4*>(dst + ad) = u.v;   // ds_write_b64
            }
        }
    };

    // ---- prologue: tile0 -> LDS, tile1 -> regs ----
    load_tile(0);
    write_tile(tiles[0]);          // compiler inserts exact vmcnt for ra
    load_tile(1);
    asm volatile("s_waitcnt lgkmcnt(0)" ::: "memory");
    __builtin_amdgcn_sched_barrier(0);
    __builtin_amdgcn_s_barrier();  // tiles[0] + pxa_lds visible to all waves

    const float m0v = (g == 0) ? 1.f : 0.f;  // rows 48,49 valid iff g==0 (mt=3,r<2)

#pragma unroll 1
    for (int i = 0; i < NIT; ++i) {
        // (a) regs (tile i+1) -> LDS buf[(i+1)&1]
        write_tile(tiles[(i + 1) & 1]);
        // (b) issue loads for tile i+2 (HBM latency hides under (c))
        load_tile(i + 2);
        __builtin_amdgcn_sched_barrier(0);   // pin load-issue ABOVE compute

        // (c) compute tile i
        const char* __restrict__ tile = tiles[i & 1];
        f32x4 acc[MT][2];
#pragma unroll
        for (int mt = 0; mt < MT; ++mt)
#pragma unroll
            for (int p = 0; p < 2; ++p) acc[mt][p] = (f32x4)0.f;

#pragma unroll
        for (int mt = 0; mt < MT; ++mt) {
            int row = 16 * mt + c;
            if (row > NN - 1) row = NN - 1;  // pad rows masked in softmax
            const int rb = row * 256;
            const int sw = (row & 7) << 4;
            f16x8 afr[KT];
#pragma unroll
            for (int kt = 0; kt < KT; ++kt)
                afr[kt] = *reinterpret_cast<const f16x8*>(
                    tile + ((rb + kt * 64 + g * 16) ^ sw));
#pragma unroll
            for (int kt = 0; kt < KT; ++kt)
#pragma unroll
                for (int p = 0; p < 2; ++p)
                    acc[mt][p] = MFMA(afr[kt], bF[p][kt], acc[mt][p]);
        }

        // softmax over n for this wave's col (no max-shift: logits ~N(0,1.4))
        {
            const float pxa = pxa_lds[i][col];
            float den = 0.f, num = 0.f;
#pragma unroll
            for (int mt = 0; mt < MT; ++mt)
#pragma unroll
                for (int r = 0; r < 4; ++r) {
                    if (mt == 3 && r >= 2) continue;     // n >= 52: never valid
                    float t = pxa + acc[mt][1][r];
                    t = fmaxf(t, 0.2f * t);              // leaky_relu(0.2)
                    float p = __expf(t);
                    if (mt == 3) p *= m0v;               // n=48,49 valid iff g==0
                    den += p;
                    num = fmaf(p, acc[mt][0][r], num);
                }
            den += __shfl_xor(den, 16); den += __shfl_xor(den, 32);
            num += __shfl_xor(num, 16); num += __shfl_xor(num, 32);
            if (g == 0 && b0 + i < (size_t)B)
                out[(b0 + i) * DD + col] = __fdividef(num, den);
        }

        // (d) all LDS ops done before any wave rewrites buffers next iter
        asm volatile("s_waitcnt lgkmcnt(0)" ::: "memory");
        __builtin_amdgcn_sched_barrier(0);
        __builtin_amdgcn_s_barrier();
    }
}

extern "C" void kernel_launch(void* const* d_in, const int* in_sizes, int n_in,
                              void* d_out, int out_size, void* d_ws, size_t ws_size,
                              hipStream_t stream) {
    const float* x   = (const float*)d_in[0];  // [B, D]
    const float* nbr = (const float*)d_in[1];  // [B, N, D]
    const float* W   = (const float*)d_in[2];  // [D, D]
    const float* A_w = (const float*)d_in[3];  // [2D, D]
    const float* A_b = (const float*)d_in[4];  // [D]
    float* out = (float*)d_out;                // [B, D]
    const int B = in_sizes[0] / DD;

    compute_WA<<<dim3(DD, 2), DD, 0, stream>>>(W, A_w);
    cvt_weights<<<3 * DD, DD, 0, stream>>>(W);
    const int grid = (B + NIT - 1) / NIT;      // 512 blocks = 2/CU, one round
    attn_mfma<<<grid, 512, 0, stream>>>(x, nbr, A_b, out, B);
}